// Round 11
// baseline (158.757 us; speedup 1.0000x reference)
//
#include <hip/hip_runtime.h>

// VQ-VAE quantize: z [32,64,64,64] NCHW fp32, codebook [512,64] fp32.
// out = quantized (8388608 fp32, NCHW) ++ loss scalar. N=131072, D=64, K=512.
//
// R19: honest 64-VGPR waves. Allocator model from R10-R18: min-waves=2
// (budget 256) -> clean 88-116 VGPR; any 128-cap config -> forced 64 + spill
// (R18: WRITE +3.3MB, 66->80us despite 2x occupancy). So reach 4 waves/EU by
// making liveness FIT 64: 1 pos-tile/wave (A-frag 16 + trackers 12 + B-frags
// 16 + acc 4 + addr ~10 = ~58 VGPR). 1024 thr = 16 waves, POSB=256, grid 512
// (2 residency rounds; round-2 staging is L2-warm + 3-phase overlapped).
// Same whole-codebook-in-LDS (153KB, 1 block/CU), 3-phase staging,
// barrier-free K-loop tail, wave-parallel fallback.
// Numerics bit-identical: 3-pass hi/lo bf16 MFMA rank, TAU=4e-3 gap ->
// np-bit-exact rescan; outputs exact gathers -> absmax 0.0.
// Tripwire: WRITE > 34MB => spill persists => revert to R17 structure.

typedef __bf16 bf8 __attribute__((ext_vector_type(8)));
typedef float  f4  __attribute__((ext_vector_type(4)));
typedef unsigned short us8 __attribute__((ext_vector_type(8)));

#define Dz    64
#define HWz   4096
#define Nz    131072
#define QSIZE ((size_t)Nz * Dz)     // 8388608
#define CROW  72                    // split-cb row stride (ushorts) = 144B
#define CB_USHORT 36864             // 512 rows x 72 (hi block); lo at +36864
#define CB_WS_BYTES 147456          // hi + lo
#define TAU   4e-3f
#define POSB  256                   // positions per block
// dynamic LDS layout (bytes)
#define OFF_CB    0
#define OFF_CN    147456            // 2048
#define OFF_IDX   149504            // 256 x int = 1024
#define OFF_ZR2   150528            // 16 waves x 64 floats = 4096
#define OFF_WSUM  154624            // 16 floats
#define OFF_NFB   154688
#define OFF_FBR   154692            // 256 x u16 = 512
#define SMEM_TOTAL 155264

#define MFMA(A, B, C) __builtin_amdgcn_mfma_f32_16x16x32_bf16(A, B, C, 0, 0, 0)

// wave-uniform LDS dest (base + lane*16), per-lane global src
__device__ __forceinline__ void gll16(const void* g, void* l) {
    __builtin_amdgcn_global_load_lds(
        (const __attribute__((address_space(1))) void*)g,
        (__attribute__((address_space(3))) void*)l, 16, 0, 0);
}

// ---------- prep: split codebook to bf16 hi/lo [hi(512x72) | lo(512x72)] ----
__global__ __launch_bounds__(64) void vq_prep(const float* __restrict__ cb,
                                              unsigned short* __restrict__ cbws,
                                              float* __restrict__ cnws) {
    const int k = blockIdx.x * 64 + threadIdx.x;    // 0..511
    const float4* row = (const float4*)(cb + (size_t)k * 64);
    {   // numpy pairwise-8 sumsq (squares round before add)
#pragma clang fp contract(off)
        float r0, r1, r2, r3, r4, r5, r6, r7;
        {
            float4 f0 = row[0], f1 = row[1];
            r0 = f0.x * f0.x; r1 = f0.y * f0.y; r2 = f0.z * f0.z; r3 = f0.w * f0.w;
            r4 = f1.x * f1.x; r5 = f1.y * f1.y; r6 = f1.z * f1.z; r7 = f1.w * f1.w;
        }
#pragma unroll
        for (int m = 1; m < 8; ++m) {
            float4 f0 = row[2 * m], f1 = row[2 * m + 1];
            r0 = r0 + f0.x * f0.x; r1 = r1 + f0.y * f0.y;
            r2 = r2 + f0.z * f0.z; r3 = r3 + f0.w * f0.w;
            r4 = r4 + f1.x * f1.x; r5 = r5 + f1.y * f1.y;
            r6 = r6 + f1.z * f1.z; r7 = r7 + f1.w * f1.w;
        }
        cnws[k] = ((r0 + r1) + (r2 + r3)) + ((r4 + r5) + (r6 + r7));
    }
    unsigned short* hi = cbws + (size_t)k * CROW;
    unsigned short* lo = cbws + CB_USHORT + (size_t)k * CROW;
    us8* hv = (us8*)hi;
    us8* lv = (us8*)lo;
#define SPLIT2(x, H, L, i)                                             \
    {   __bf16 h = (__bf16)(x); float rr = (x) - (float)h;             \
        H[i] = __builtin_bit_cast(unsigned short, h);                  \
        L[i] = __builtin_bit_cast(unsigned short, (__bf16)rr); }
#pragma unroll
    for (int c = 0; c < 8; ++c) {
        float4 f0 = row[2 * c], f1 = row[2 * c + 1];
        us8 h8, l8;
        SPLIT2(f0.x, h8, l8, 0) SPLIT2(f0.y, h8, l8, 1)
        SPLIT2(f0.z, h8, l8, 2) SPLIT2(f0.w, h8, l8, 3)
        SPLIT2(f1.x, h8, l8, 4) SPLIT2(f1.y, h8, l8, 5)
        SPLIT2(f1.z, h8, l8, 6) SPLIT2(f1.w, h8, l8, 7)
        hv[c] = h8;
        lv[c] = l8;
    }
#undef SPLIT2
}

// ---------- main ----------
// best/second update: order matters (second from OLD best). med3 is exact:
// with S>=B, med3(S,B,vv) == min(max(B,vv), S).
#define UPDR(ACCE, B, K, S)                                            \
    {   const float vv = __builtin_fmaf(ACCE, -2.0f, cnv);             \
        S = __builtin_amdgcn_fmed3f(S, B, vv);                         \
        K = (vv < B) ? kcand : K;                                      \
        B = fminf(B, vv); }

#define REDR(B, K, S)                                                  \
    _Pragma("unroll")                                                  \
    for (int mm = 1; mm < 16; mm <<= 1) {                              \
        const float ob = __shfl_xor(B, mm, 64);                        \
        const int   ok = __shfl_xor(K, mm, 64);                        \
        const float os = __shfl_xor(S, mm, 64);                        \
        S = fminf(fminf(S, os), fmaxf(B, ob));                         \
        K = (ob < B) ? ok : K;                                         \
        B = fminf(B, ob); }

// per position-tile T: A-frags (hi/lo x 2 k-chunks) + best/second trackers
#define DECLT(T)                                                       \
    bf8 ah##T##0, ah##T##1, al##T##0, al##T##1;                        \
    float bd##T##0 = INF, bd##T##1 = INF, bd##T##2 = INF, bd##T##3 = INF; \
    float sd##T##0 = INF, sd##T##1 = INF, sd##T##2 = INF, sd##T##3 = INF; \
    int   bk##T##0 = 0, bk##T##1 = 0, bk##T##2 = 0, bk##T##3 = 0;

#define BUILDT(T, P)                                                   \
    _Pragma("unroll")                                                  \
    for (int j = 0; j < 8; ++j) {                                      \
        const float v0 = zq[(size_t)(q * 8 + j) * HWz + (P)];          \
        const float v1 = zq[(size_t)(32 + q * 8 + j) * HWz + (P)];     \
        const __bf16 h0 = (__bf16)v0, h1 = (__bf16)v1;                 \
        ah##T##0[j] = h0; al##T##0[j] = (__bf16)(v0 - (float)h0);      \
        ah##T##1[j] = h1; al##T##1[j] = (__bf16)(v1 - (float)h1);      \
    }

#define TILE_STEP(T)                                                   \
    {   f4 acc = {0.f, 0.f, 0.f, 0.f};                                 \
        acc = MFMA(ah##T##0, bh0, acc); acc = MFMA(ah##T##1, bh1, acc);\
        acc = MFMA(al##T##0, bh0, acc); acc = MFMA(al##T##1, bh1, acc);\
        acc = MFMA(ah##T##0, bl0, acc); acc = MFMA(ah##T##1, bl1, acc);\
        UPDR(acc[0], bd##T##0, bk##T##0, sd##T##0)                     \
        UPDR(acc[1], bd##T##1, bk##T##1, sd##T##1)                     \
        UPDR(acc[2], bd##T##2, bk##T##2, sd##T##2)                     \
        UPDR(acc[3], bd##T##3, bk##T##3, sd##T##3) }

#define REDT(T)                                                        \
    REDR(bd##T##0, bk##T##0, sd##T##0) REDR(bd##T##1, bk##T##1, sd##T##1) \
    REDR(bd##T##2, bk##T##2, sd##T##2) REDR(bd##T##3, bk##T##3, sd##T##3)

#define FLAGT(T, OFF)                                                  \
    idx_s[base + (OFF) + 0] = (sd##T##0 - bd##T##0 <= TAU) ? -1 : bk##T##0; \
    idx_s[base + (OFF) + 1] = (sd##T##1 - bd##T##1 <= TAU) ? -1 : bk##T##1; \
    idx_s[base + (OFF) + 2] = (sd##T##2 - bd##T##2 <= TAU) ? -1 : bk##T##2; \
    idx_s[base + (OFF) + 3] = (sd##T##3 - bd##T##3 <= TAU) ? -1 : bk##T##3;

#define KRANGE(S0, S1)                                                 \
    _Pragma("unroll 4")                                                \
    for (int s = (S0); s < (S1); ++s) {                                \
        const int nlane = 16 * s + m16;                                \
        const unsigned short* p = cbL + nlane * CROW + q * 8;          \
        const bf8 bh0 = *(const bf8*)(p);                              \
        const bf8 bh1 = *(const bf8*)(p + 32);                         \
        const bf8 bl0 = *(const bf8*)(p + CB_USHORT);                  \
        const bf8 bl1 = *(const bf8*)(p + CB_USHORT + 32);             \
        const float cnv = cn_s[nlane];                                 \
        const int kcand = nlane;                                       \
        TILE_STEP(A)                                                   \
    }

__global__ __launch_bounds__(1024) void vq_main(
    const float* __restrict__ z, const float* __restrict__ cb,
    const unsigned short* __restrict__ cbws, const float* __restrict__ cnws,
    float* __restrict__ out, float* __restrict__ loss_accum,
    unsigned int* __restrict__ done_counter) {
    extern __shared__ __attribute__((aligned(16))) char smem[];
    unsigned short* cbL   = (unsigned short*)(smem + OFF_CB);
    float* cn_s           = (float*)(smem + OFF_CN);
    int*   idx_s          = (int*)(smem + OFF_IDX);
    float* wsum           = (float*)(smem + OFF_WSUM);
    int*   nfb            = (int*)(smem + OFF_NFB);
    unsigned short* fbrow = (unsigned short*)(smem + OFF_FBR);

    const int t  = threadIdx.x;
    const int w  = t >> 6;      // 0..15
    const int l  = t & 63;
    const int q  = l >> 4;
    const int m16 = l & 15;
    const int n0g = blockIdx.x * POSB;
    const int b   = n0g >> 12;
    const int s0  = n0g & 4095;
    const float* zB = z + (size_t)b * (Dz * HWz);
    const char* tsrc = (const char*)cbws;
    char* tdst = smem + OFF_CB;
#define STAGE_CHUNK(c) gll16(tsrc + (size_t)(c) * 1024 + l * 16, tdst + (c) * 1024)

    // ---- P1: stage codes 0..127 (hi chunks 0..17, lo chunks 72..89) + cn.
    {
#pragma unroll
        for (int i = 0; i < 3; ++i) {
            const int ci = w + 16 * i;      // 0..47
            if (ci < 18)       STAGE_CHUNK(ci);
            else if (ci < 36)  STAGE_CHUNK(72 + ci - 18);
            else if (ci < 38)  gll16((const char*)cnws + (ci - 36) * 1024 + l * 16,
                                     smem + OFF_CN + (ci - 36) * 1024);
        }
        if (t == 0) *nfb = 0;
    }

    // ---- build A fragment straight from global (overlaps P1 staging)
    const float INF = __builtin_inff();
    DECLT(A)
    {
        const int pA = 16 * w + m16;
        const float* zq = zB + s0;
        BUILDT(A, pA)
    }
    __syncthreads();    // P1 data + A-build loads drained

    // ---- P2a: issue codes 128..255; compute steps 0..7 (codes 0..127)
#pragma unroll
    for (int i = 0; i < 3; ++i) {
        const int ci = w + 16 * i;          // 0..47
        if (ci < 18)       STAGE_CHUNK(18 + ci);
        else if (ci < 36)  STAGE_CHUNK(90 + ci - 18);
    }
    KRANGE(0, 8)
    __syncthreads();    // codes 128..255 landed (loads covered by steps 0..7)

    // ---- P2b: issue codes 256..511; compute steps 8..15 (codes 128..255)
#pragma unroll
    for (int i = 0; i < 5; ++i) {
        const int ci = w + 16 * i;          // 0..79
        if (ci < 36)      STAGE_CHUNK(36 + ci);
        else if (ci < 72) STAGE_CHUNK(108 + ci - 36);
    }
    KRANGE(8, 16)
    __syncthreads();    // codes 256..511 landed

    // ---- steps 16..31: barrier-free tail
    KRANGE(16, 32)

    // ---- cross-lane reduce (16-lane groups hold one row each) + flag.
    REDT(A)
    if (m16 == 0) {
        const int base = 16 * w + 4 * q;
        FLAGT(A, 0)
    }
    __syncthreads();

    // ---- compact flagged rows (skip scan when clean)
    if (t < POSB && idx_s[t] < 0) {
        const int s = atomicAdd(nfb, 1);
        fbrow[s] = (unsigned short)t;
    }
    __syncthreads();
    const int nfbv = *nfb;

    // ---- fallback: np-bit-exact rescan, WAVE-PARALLEL over flagged rows.
    // Wave w handles rows fi = w, w+16, ...; lane l rescans codes l+64h
    // (ascending h => strict < keeps lowest k). No barriers in the loop.
    {
        float* zr = (float*)(smem + OFF_ZR2) + w * 64;
        for (int fi = w; fi < nfbv; fi += 16) {
            const int row = fbrow[fi];
            zr[l] = zB[(size_t)l * HWz + s0 + row];
            asm volatile("s_waitcnt lgkmcnt(0)" ::: "memory");
            __builtin_amdgcn_sched_barrier(0);   // rule-#18 fence
            float zn;
            {   // np pairwise-8 znorm (broadcast LDS reads, same expr as ever)
#pragma clang fp contract(off)
                float r0, r1, r2, r3, r4, r5, r6, r7;
                r0 = zr[0]*zr[0]; r1 = zr[1]*zr[1];
                r2 = zr[2]*zr[2]; r3 = zr[3]*zr[3];
                r4 = zr[4]*zr[4]; r5 = zr[5]*zr[5];
                r6 = zr[6]*zr[6]; r7 = zr[7]*zr[7];
#pragma unroll
                for (int m = 1; m < 8; ++m) {
                    float v0 = zr[8*m+0], v1 = zr[8*m+1];
                    float v2 = zr[8*m+2], v3 = zr[8*m+3];
                    float v4 = zr[8*m+4], v5 = zr[8*m+5];
                    float v6 = zr[8*m+6], v7 = zr[8*m+7];
                    r0 = r0 + v0*v0; r1 = r1 + v1*v1;
                    r2 = r2 + v2*v2; r3 = r3 + v3*v3;
                    r4 = r4 + v4*v4; r5 = r5 + v5*v5;
                    r6 = r6 + v6*v6; r7 = r7 + v7*v7;
                }
                zn = ((r0 + r1) + (r2 + r3)) + ((r4 + r5) + (r6 + r7));
            }
            float bd = INF; int bk = 0;
#pragma unroll
            for (int h = 0; h < 8; ++h) {
                const int k = l + 64 * h;
                const float4* C = (const float4*)(cb + (size_t)k * 64);
                float a = 0.f;
#pragma unroll
                for (int i = 0; i < 16; ++i) {
                    const float4 c4 = C[i];
                    a = __builtin_fmaf(zr[4*i+0], c4.x, a);
                    a = __builtin_fmaf(zr[4*i+1], c4.y, a);
                    a = __builtin_fmaf(zr[4*i+2], c4.z, a);
                    a = __builtin_fmaf(zr[4*i+3], c4.w, a);
                }
                const float d2 = (zn - 2.0f * a) + cn_s[k];
                if (h == 0 || d2 < bd) { bd = d2; bk = k; }
            }
#pragma unroll
            for (int mm = 1; mm < 64; mm <<= 1) {
                const float ob = __shfl_xor(bd, mm, 64);
                const int   ok = __shfl_xor(bk, mm, 64);
                if (ob < bd || (ob == bd && ok < bk)) { bd = ob; bk = ok; }
            }
            if (l == 0) idx_s[row] = bk;
        }
    }
    __syncthreads();

    // ---- epilogue: gather code, write q_st (NCHW coalesced), loss.
    // 4 threads per position, 16 d's each. y re-read from global (L3-warm),
    // bitwise same values as z.
    const int p  = t & 255;
    const int d0 = (t >> 8) * 16;
    const int myidx = idx_s[p];
    const float* qrow = cb + (size_t)myidx * 64 + d0;
    const float* zc = zB + s0 + p;
    float* oB = out + (size_t)b * (Dz * HWz) + s0 + p;
    float lsum = 0.f;
#pragma unroll
    for (int j = 0; j < 4; ++j) {
        const int d = d0 + 4 * j;
        const float4 q4 = *(const float4*)(qrow + 4 * j);
        const float y0 = zc[(size_t)(d + 0) * HWz];
        const float y1 = zc[(size_t)(d + 1) * HWz];
        const float y2 = zc[(size_t)(d + 2) * HWz];
        const float y3 = zc[(size_t)(d + 3) * HWz];
        const float e0 = y0 - q4.x, e1 = y1 - q4.y;
        const float e2 = y2 - q4.z, e3 = y3 - q4.w;
        lsum += e0 * e0; lsum += e1 * e1; lsum += e2 * e2; lsum += e3 * e3;
        oB[(size_t)(d + 0) * HWz] = y0 + (q4.x - y0);
        oB[(size_t)(d + 1) * HWz] = y1 + (q4.y - y1);
        oB[(size_t)(d + 2) * HWz] = y2 + (q4.z - y2);
        oB[(size_t)(d + 3) * HWz] = y3 + (q4.w - y3);
    }
#pragma unroll
    for (int off = 32; off > 0; off >>= 1) lsum += __shfl_down(lsum, off, 64);
    if (l == 0) wsum[w] = lsum;
    __syncthreads();
    if (t == 0) {
        float tot = 0.f;
#pragma unroll
        for (int i = 0; i < 16; i += 4)
            tot += ((wsum[i] + wsum[i + 1]) + (wsum[i + 2] + wsum[i + 3]));
        atomicAdd(loss_accum, tot);
        __threadfence();
        unsigned int ticket = atomicAdd(done_counter, 1u);
        if (ticket == gridDim.x - 1) {
            __threadfence();
            float total = atomicAdd(loss_accum, 0.0f);
            float X = total / (float)QSIZE;
            out[QSIZE] = X + 0.25f * X;
        }
    }
}

extern "C" void kernel_launch(void* const* d_in, const int* in_sizes, int n_in,
                              void* d_out, int out_size, void* d_ws, size_t ws_size,
                              hipStream_t stream) {
    const float* z  = (const float*)d_in[0];
    const float* cb = (const float*)d_in[1];
    float* out = (float*)d_out;
    unsigned short* cbws = (unsigned short*)d_ws;
    float* cnws = (float*)((char*)d_ws + CB_WS_BYTES);
    float* lossp = (float*)((char*)d_ws + CB_WS_BYTES + 2048);
    unsigned int* donep = (unsigned int*)(lossp + 1);
    static bool attr_done = false;
    if (!attr_done) {
        (void)hipFuncSetAttribute((const void*)vq_main,
                                  hipFuncAttributeMaxDynamicSharedMemorySize,
                                  SMEM_TOTAL);
        attr_done = true;
    }
    hipMemsetAsync(lossp, 0, 8, stream);
    vq_prep<<<8, 64, 0, stream>>>(cb, cbws, cnws);
    vq_main<<<Nz / POSB, 1024, SMEM_TOTAL, stream>>>(z, cb, cbws, cnws, out,
                                                     lossp, donep);
}

// Round 12
// 135.861 us; speedup vs baseline: 1.1685x; 1.1685x over previous
//
#include <hip/hip_runtime.h>

// VQ-VAE quantize: z [32,64,64,64] NCHW fp32, codebook [512,64] fp32.
// out = quantized (8388608 fp32, NCHW) ++ loss scalar. N=131072, D=64, K=512.
//
// R20: single-kernel fusion. R19 closed the occupancy arc (LDS floor scales
// with waves; R17's 4-tile/8-wave point is optimal). Remaining un-attacked
// cost: the 59-71us bench-vs-main gap (vq_prep + extra launch + ws trip).
// Fuse prep INTO vq_main: thread t (=code t) reads its cb row (L2-broadcast),
// computes cn (verbatim np pairwise-8) and bf16 hi/lo split (verbatim
// SPLIT2), ds_writes directly into the LDS codebook layout. Replaces
// vq_prep + all gll16 staging; ONE barrier then 32 barrier-free K-steps.
// A-build z-loads issue first so both streams overlap before the barrier.
// LDS contents + cn bitwise identical to R17 -> numerics unchanged:
// 3-pass hi/lo bf16 MFMA rank, TAU=4e-3 gap -> np-bit-exact wave-parallel
// rescan; outputs exact gathers -> absmax 0.0.
// Tripwire: WRITE > 34MB => spill => revert to R17.

typedef __bf16 bf8 __attribute__((ext_vector_type(8)));
typedef float  f4  __attribute__((ext_vector_type(4)));
typedef unsigned short us8 __attribute__((ext_vector_type(8)));

#define Dz    64
#define HWz   4096
#define Nz    131072
#define QSIZE ((size_t)Nz * Dz)     // 8388608
#define CROW  72                    // split-cb row stride (ushorts) = 144B
#define CB_USHORT 36864             // 512 rows x 72 (hi block); lo at +36864
#define TAU   4e-3f
#define POSB  512                   // positions per block
// dynamic LDS layout (bytes)
#define OFF_CB    0
#define OFF_CN    147456            // 512 f32
#define OFF_IDX   149504            // 512 int
#define OFF_ZR2   151552            // 8 waves x 64 f32
#define OFF_WSUM  153600            // 8 f32
#define OFF_NFB   153632
#define OFF_FBR   153636            // 512 u16
#define SMEM_TOTAL 154688

#define MFMA(A, B, C) __builtin_amdgcn_mfma_f32_16x16x32_bf16(A, B, C, 0, 0, 0)

// ---------- main ----------
// best/second update: order matters (second from OLD best). med3 is exact:
// with S>=B, med3(S,B,vv) == min(max(B,vv), S).
#define UPDR(ACCE, B, K, S)                                            \
    {   const float vv = __builtin_fmaf(ACCE, -2.0f, cnv);             \
        S = __builtin_amdgcn_fmed3f(S, B, vv);                         \
        K = (vv < B) ? kcand : K;                                      \
        B = fminf(B, vv); }

#define REDR(B, K, S)                                                  \
    _Pragma("unroll")                                                  \
    for (int mm = 1; mm < 16; mm <<= 1) {                              \
        const float ob = __shfl_xor(B, mm, 64);                        \
        const int   ok = __shfl_xor(K, mm, 64);                        \
        const float os = __shfl_xor(S, mm, 64);                        \
        S = fminf(fminf(S, os), fmaxf(B, ob));                         \
        K = (ob < B) ? ok : K;                                         \
        B = fminf(B, ob); }

// per position-tile T: A-frags (hi/lo x 2 k-chunks) + best/second trackers
#define DECLT(T)                                                       \
    bf8 ah##T##0, ah##T##1, al##T##0, al##T##1;                        \
    float bd##T##0 = INF, bd##T##1 = INF, bd##T##2 = INF, bd##T##3 = INF; \
    float sd##T##0 = INF, sd##T##1 = INF, sd##T##2 = INF, sd##T##3 = INF; \
    int   bk##T##0 = 0, bk##T##1 = 0, bk##T##2 = 0, bk##T##3 = 0;

#define BUILDT(T, P)                                                   \
    _Pragma("unroll")                                                  \
    for (int j = 0; j < 8; ++j) {                                      \
        const float v0 = zq[(size_t)(q * 8 + j) * HWz + (P)];          \
        const float v1 = zq[(size_t)(32 + q * 8 + j) * HWz + (P)];     \
        const __bf16 h0 = (__bf16)v0, h1 = (__bf16)v1;                 \
        ah##T##0[j] = h0; al##T##0[j] = (__bf16)(v0 - (float)h0);      \
        ah##T##1[j] = h1; al##T##1[j] = (__bf16)(v1 - (float)h1);      \
    }

#define TILE_STEP(T)                                                   \
    {   f4 acc = {0.f, 0.f, 0.f, 0.f};                                 \
        acc = MFMA(ah##T##0, bh0, acc); acc = MFMA(ah##T##1, bh1, acc);\
        acc = MFMA(al##T##0, bh0, acc); acc = MFMA(al##T##1, bh1, acc);\
        acc = MFMA(ah##T##0, bl0, acc); acc = MFMA(ah##T##1, bl1, acc);\
        UPDR(acc[0], bd##T##0, bk##T##0, sd##T##0)                     \
        UPDR(acc[1], bd##T##1, bk##T##1, sd##T##1)                     \
        UPDR(acc[2], bd##T##2, bk##T##2, sd##T##2)                     \
        UPDR(acc[3], bd##T##3, bk##T##3, sd##T##3) }

#define REDT(T)                                                        \
    REDR(bd##T##0, bk##T##0, sd##T##0) REDR(bd##T##1, bk##T##1, sd##T##1) \
    REDR(bd##T##2, bk##T##2, sd##T##2) REDR(bd##T##3, bk##T##3, sd##T##3)

#define FLAGT(T, OFF)                                                  \
    idx_s[base + (OFF) + 0] = (sd##T##0 - bd##T##0 <= TAU) ? -1 : bk##T##0; \
    idx_s[base + (OFF) + 1] = (sd##T##1 - bd##T##1 <= TAU) ? -1 : bk##T##1; \
    idx_s[base + (OFF) + 2] = (sd##T##2 - bd##T##2 <= TAU) ? -1 : bk##T##2; \
    idx_s[base + (OFF) + 3] = (sd##T##3 - bd##T##3 <= TAU) ? -1 : bk##T##3;

__global__ __launch_bounds__(512, 2) void vq_main(
    const float* __restrict__ z, const float* __restrict__ cb,
    float* __restrict__ out, float* __restrict__ loss_accum,
    unsigned int* __restrict__ done_counter) {
    extern __shared__ __attribute__((aligned(16))) char smem[];
    unsigned short* cbL   = (unsigned short*)(smem + OFF_CB);
    float* cn_s           = (float*)(smem + OFF_CN);
    int*   idx_s          = (int*)(smem + OFF_IDX);
    float* wsum           = (float*)(smem + OFF_WSUM);
    int*   nfb            = (int*)(smem + OFF_NFB);
    unsigned short* fbrow = (unsigned short*)(smem + OFF_FBR);

    const int t  = threadIdx.x;
    const int w  = t >> 6;      // 0..7
    const int l  = t & 63;
    const int q  = l >> 4;
    const int m16 = l & 15;
    const int n0g = blockIdx.x * POSB;
    const int b   = n0g >> 12;
    const int s0  = n0g & 4095;
    const float* zB = z + (size_t)b * (Dz * HWz);

    // ---- build A fragments straight from global (issue z loads first)
    const float INF = __builtin_inff();
    DECLT(A) DECLT(B) DECLT(C) DECLT(D)
    {
        const int pA = 64 * w + m16;
        const float* zq = zB + s0;
        BUILDT(A, pA) BUILDT(B, pA + 16) BUILDT(C, pA + 32) BUILDT(D, pA + 48)
    }

    // ---- fused prep: thread t = code t. cn (verbatim np pairwise-8) +
    // bf16 hi/lo split (verbatim SPLIT2) written straight into LDS layout.
    // cb reads are an L2-broadcast (every block reads the same 128KB).
    {
        const float4* row = (const float4*)(cb + (size_t)t * 64);
        {
#pragma clang fp contract(off)
            float r0, r1, r2, r3, r4, r5, r6, r7;
            {
                float4 f0 = row[0], f1 = row[1];
                r0 = f0.x * f0.x; r1 = f0.y * f0.y;
                r2 = f0.z * f0.z; r3 = f0.w * f0.w;
                r4 = f1.x * f1.x; r5 = f1.y * f1.y;
                r6 = f1.z * f1.z; r7 = f1.w * f1.w;
            }
#pragma unroll
            for (int m = 1; m < 8; ++m) {
                float4 f0 = row[2 * m], f1 = row[2 * m + 1];
                r0 = r0 + f0.x * f0.x; r1 = r1 + f0.y * f0.y;
                r2 = r2 + f0.z * f0.z; r3 = r3 + f0.w * f0.w;
                r4 = r4 + f1.x * f1.x; r5 = r5 + f1.y * f1.y;
                r6 = r6 + f1.z * f1.z; r7 = r7 + f1.w * f1.w;
            }
            cn_s[t] = ((r0 + r1) + (r2 + r3)) + ((r4 + r5) + (r6 + r7));
        }
        unsigned short* hi = cbL + (size_t)t * CROW;
        unsigned short* lo = cbL + CB_USHORT + (size_t)t * CROW;
        us8* hv = (us8*)hi;
        us8* lv = (us8*)lo;
#define SPLIT2(x, H, L, i)                                             \
    {   __bf16 h = (__bf16)(x); float rr = (x) - (float)h;             \
        H[i] = __builtin_bit_cast(unsigned short, h);                  \
        L[i] = __builtin_bit_cast(unsigned short, (__bf16)rr); }
#pragma unroll
        for (int c = 0; c < 8; ++c) {
            float4 f0 = row[2 * c], f1 = row[2 * c + 1];
            us8 h8, l8;
            SPLIT2(f0.x, h8, l8, 0) SPLIT2(f0.y, h8, l8, 1)
            SPLIT2(f0.z, h8, l8, 2) SPLIT2(f0.w, h8, l8, 3)
            SPLIT2(f1.x, h8, l8, 4) SPLIT2(f1.y, h8, l8, 5)
            SPLIT2(f1.z, h8, l8, 6) SPLIT2(f1.w, h8, l8, 7)
            hv[c] = h8;
            lv[c] = l8;
        }
#undef SPLIT2
    }
    if (t == 0) *nfb = 0;
    __syncthreads();    // codebook + cn in LDS; A-frags built. ONLY barrier
                        // before the reduce phase.

    // ---- K loop: 32 steps x 16 codes, all from LDS, ZERO barriers.
#pragma unroll 4
    for (int s = 0; s < 32; ++s) {
        const int nlane = 16 * s + m16;
        const unsigned short* p = cbL + nlane * CROW + q * 8;
        const bf8 bh0 = *(const bf8*)(p);
        const bf8 bh1 = *(const bf8*)(p + 32);
        const bf8 bl0 = *(const bf8*)(p + CB_USHORT);
        const bf8 bl1 = *(const bf8*)(p + CB_USHORT + 32);
        const float cnv = cn_s[nlane];
        const int kcand = nlane;
        TILE_STEP(A) TILE_STEP(B) TILE_STEP(C) TILE_STEP(D)
    }

    // ---- cross-lane reduce (16-lane groups hold one row each) + flag.
    REDT(A) REDT(B) REDT(C) REDT(D)
    if (m16 == 0) {
        const int base = 64 * w + 4 * q;
        FLAGT(A, 0) FLAGT(B, 16) FLAGT(C, 32) FLAGT(D, 48)
    }
    __syncthreads();

    // ---- compact flagged rows (skip scan when clean)
    if (idx_s[t] < 0) {
        const int s = atomicAdd(nfb, 1);
        fbrow[s] = (unsigned short)t;
    }
    __syncthreads();
    const int nfbv = *nfb;

    // ---- fallback: np-bit-exact rescan, WAVE-PARALLEL over flagged rows.
    // Wave w handles rows fi = w, w+8, ...; lane l rescans codes l+64h
    // (ascending h => strict < keeps lowest k). No barriers in the loop.
    {
        float* zr = (float*)(smem + OFF_ZR2) + w * 64;
        for (int fi = w; fi < nfbv; fi += 8) {
            const int row = fbrow[fi];
            zr[l] = zB[(size_t)l * HWz + s0 + row];
            asm volatile("s_waitcnt lgkmcnt(0)" ::: "memory");
            __builtin_amdgcn_sched_barrier(0);   // rule-#18 fence
            float zn;
            {   // np pairwise-8 znorm (broadcast LDS reads, same expr as ever)
#pragma clang fp contract(off)
                float r0, r1, r2, r3, r4, r5, r6, r7;
                r0 = zr[0]*zr[0]; r1 = zr[1]*zr[1];
                r2 = zr[2]*zr[2]; r3 = zr[3]*zr[3];
                r4 = zr[4]*zr[4]; r5 = zr[5]*zr[5];
                r6 = zr[6]*zr[6]; r7 = zr[7]*zr[7];
#pragma unroll
                for (int m = 1; m < 8; ++m) {
                    float v0 = zr[8*m+0], v1 = zr[8*m+1];
                    float v2 = zr[8*m+2], v3 = zr[8*m+3];
                    float v4 = zr[8*m+4], v5 = zr[8*m+5];
                    float v6 = zr[8*m+6], v7 = zr[8*m+7];
                    r0 = r0 + v0*v0; r1 = r1 + v1*v1;
                    r2 = r2 + v2*v2; r3 = r3 + v3*v3;
                    r4 = r4 + v4*v4; r5 = r5 + v5*v5;
                    r6 = r6 + v6*v6; r7 = r7 + v7*v7;
                }
                zn = ((r0 + r1) + (r2 + r3)) + ((r4 + r5) + (r6 + r7));
            }
            float bd = INF; int bk = 0;
#pragma unroll
            for (int h = 0; h < 8; ++h) {
                const int k = l + 64 * h;
                const float4* C = (const float4*)(cb + (size_t)k * 64);
                float a = 0.f;
#pragma unroll
                for (int i = 0; i < 16; ++i) {
                    const float4 c4 = C[i];
                    a = __builtin_fmaf(zr[4*i+0], c4.x, a);
                    a = __builtin_fmaf(zr[4*i+1], c4.y, a);
                    a = __builtin_fmaf(zr[4*i+2], c4.z, a);
                    a = __builtin_fmaf(zr[4*i+3], c4.w, a);
                }
                const float d2 = (zn - 2.0f * a) + cn_s[k];
                if (h == 0 || d2 < bd) { bd = d2; bk = k; }
            }
#pragma unroll
            for (int mm = 1; mm < 64; mm <<= 1) {
                const float ob = __shfl_xor(bd, mm, 64);
                const int   ok = __shfl_xor(bk, mm, 64);
                if (ob < bd || (ob == bd && ok < bk)) { bd = ob; bk = ok; }
            }
            if (l == 0) idx_s[row] = bk;
        }
    }
    __syncthreads();

    // ---- epilogue: gather code, write q_st (NCHW coalesced), loss.
    // One thread per position, full 64-d column. y re-read from global
    // (coalesced, L3-warm) -- bitwise same values as z.
    const int myidx = idx_s[t];
    const float* qrow = cb + (size_t)myidx * 64;
    const float* zc = zB + s0 + t;
    float* oB = out + (size_t)b * (Dz * HWz) + s0 + t;
    float lsum = 0.f;
#pragma unroll
    for (int j = 0; j < 16; ++j) {
        const int d = 4 * j;
        const float4 q4 = *(const float4*)(qrow + d);
        const float y0 = zc[(size_t)(d + 0) * HWz];
        const float y1 = zc[(size_t)(d + 1) * HWz];
        const float y2 = zc[(size_t)(d + 2) * HWz];
        const float y3 = zc[(size_t)(d + 3) * HWz];
        const float e0 = y0 - q4.x, e1 = y1 - q4.y;
        const float e2 = y2 - q4.z, e3 = y3 - q4.w;
        lsum += e0 * e0; lsum += e1 * e1; lsum += e2 * e2; lsum += e3 * e3;
        oB[(size_t)(d + 0) * HWz] = y0 + (q4.x - y0);
        oB[(size_t)(d + 1) * HWz] = y1 + (q4.y - y1);
        oB[(size_t)(d + 2) * HWz] = y2 + (q4.z - y2);
        oB[(size_t)(d + 3) * HWz] = y3 + (q4.w - y3);
    }
#pragma unroll
    for (int off = 32; off > 0; off >>= 1) lsum += __shfl_down(lsum, off, 64);
    if (l == 0) wsum[w] = lsum;
    __syncthreads();
    if (t == 0) {
        float tot = ((wsum[0] + wsum[1]) + (wsum[2] + wsum[3]))
                  + ((wsum[4] + wsum[5]) + (wsum[6] + wsum[7]));
        atomicAdd(loss_accum, tot);
        __threadfence();
        unsigned int ticket = atomicAdd(done_counter, 1u);
        if (ticket == gridDim.x - 1) {
            __threadfence();
            float total = atomicAdd(loss_accum, 0.0f);
            float X = total / (float)QSIZE;
            out[QSIZE] = X + 0.25f * X;
        }
    }
}

extern "C" void kernel_launch(void* const* d_in, const int* in_sizes, int n_in,
                              void* d_out, int out_size, void* d_ws, size_t ws_size,
                              hipStream_t stream) {
    const float* z  = (const float*)d_in[0];
    const float* cb = (const float*)d_in[1];
    float* out = (float*)d_out;
    float* lossp = (float*)d_ws;
    unsigned int* donep = (unsigned int*)(lossp + 1);
    static bool attr_done = false;
    if (!attr_done) {
        (void)hipFuncSetAttribute((const void*)vq_main,
                                  hipFuncAttributeMaxDynamicSharedMemorySize,
                                  SMEM_TOTAL);
        attr_done = true;
    }
    hipMemsetAsync(lossp, 0, 8, stream);
    vq_main<<<Nz / POSB, 512, SMEM_TOTAL, stream>>>(z, cb, out, lossp, donep);
}